// Round 6
// baseline (4935.252 us; speedup 1.0000x reference)
//
#include <hip/hip_runtime.h>
#include <hip/hip_bf16.h>

// GRU: SEQ=64, BATCH=64, HID=EMB=512, VOCAB=10000, LAYERS=2
// Outputs: logits (64,64,10000) f32 then h_final (2,64,512) f32, concat flat.

#define SEQ 64
#define NBG 16   // persistent-GRU grid: 16 blocks x 512 threads

typedef short s16x8 __attribute__((ext_vector_type(8)));   // 8 bf16 (4 VGPRs)
typedef float f32x4 __attribute__((ext_vector_type(4)));
typedef int   i32x4 __attribute__((ext_vector_type(4)));
typedef unsigned long long ull;

static __device__ __forceinline__ unsigned short f2bf(float f){
    unsigned int u = __float_as_uint(f);
    return (unsigned short)((u + 0x7FFFu + ((u >> 16) & 1u)) >> 16);  // RNE
}
static __device__ __forceinline__ float bf2f(unsigned short s){
    return __uint_as_float(((unsigned int)s) << 16);
}
static __device__ __forceinline__ float sigm(float x){
    return __fdividef(1.0f, 1.0f + __expf(-x));
}
static __device__ __forceinline__ float tanh_fast(float x){
    float ax = fabsf(x);
    float e = __expf(-2.0f * ax);
    float r = __fdividef(1.0f - e, 1.0f + e);
    return copysignf(r, x);
}

// ---- coherent (sc0 sc1 = MALL-coherent, cache-bypassing) asm access --------
// Loads are issued WITHOUT per-load waits; one SC_WAIT() drains the batch.
#define SC_LD16_NW(T,A) \
  asm volatile("global_load_dwordx4 %0, %1, off sc0 sc1" : "=&v"(T) : "v"(A) : "memory")
#define SC_LD8_NW(T,A) \
  asm volatile("global_load_dwordx2 %0, %1, off sc0 sc1" : "=&v"(T) : "v"(A) : "memory")
#define SC_WAIT() asm volatile("s_waitcnt vmcnt(0)" ::: "memory")

static __device__ __forceinline__ void sc_st8(void* p, ull v){
    asm volatile("global_store_dwordx2 %0, %1, off sc0 sc1" :: "v"(p), "v"(v) : "memory");
}
static __device__ __forceinline__ void sc_st16(void* p, f32x4 v){
    asm volatile("global_store_dwordx4 %0, %1, off sc0 sc1" :: "v"(p), "v"(v) : "memory");
}
static __device__ __forceinline__ f32x4 sc_ld16(const void* p){
    f32x4 v;
    asm volatile("global_load_dwordx4 %0, %1, off sc0 sc1\n\ts_waitcnt vmcnt(0)"
                 : "=v"(v) : "v"(p) : "memory");
    return v;
}
static __device__ __forceinline__ ull pack4bf(const float v[4]){
    union { ull u; unsigned short s[4]; } x;
    x.s[0]=f2bf(v[0]); x.s[1]=f2bf(v[1]); x.s[2]=f2bf(v[2]); x.s[3]=f2bf(v[3]);
    return x.u;
}

// ---------------------------------------------------------------- prep ------
__global__ void prep_kernel(const int* __restrict__ inputs, const float* __restrict__ hidden,
    const float* __restrict__ emb, const float* __restrict__ Wx, const float* __restrict__ Uh,
    const float* __restrict__ Uht, const float* __restrict__ dec_w,
    unsigned short* __restrict__ emb_bf, unsigned short* __restrict__ WxT0,
    unsigned short* __restrict__ UhT0, unsigned short* __restrict__ UhtT0,
    unsigned short* __restrict__ B3T, unsigned short* __restrict__ UhtT1,
    unsigned short* __restrict__ decpad,
    float* __restrict__ HH, unsigned short* __restrict__ HHbf, unsigned int* __restrict__ barzone)
{
    const long long stride = (long long)gridDim.x * blockDim.x;
    const long long t0 = (long long)blockIdx.x * blockDim.x + threadIdx.x;
    for (long long i = t0; i < 4096LL*512; i += stride){
        int r = (int)(i >> 9), k = (int)(i & 511);
        emb_bf[i] = f2bf(emb[(long long)inputs[r]*512 + k]);
    }
    for (long long i = t0; i < 1536LL*512; i += stride){
        int n = (int)(i >> 9), k = (int)(i & 511);
        WxT0[i] = f2bf(Wx[(long long)k*1536 + n]);
    }
    for (long long i = t0; i < 1024LL*512; i += stride){
        int n = (int)(i >> 9), k = (int)(i & 511);
        UhT0[i] = f2bf(Uh[(long long)k*1024 + n]);
    }
    for (long long i = t0; i < 512LL*512; i += stride){
        int n = (int)(i >> 9), k = (int)(i & 511);
        UhtT0[i] = f2bf(Uht[(long long)k*512 + n]);
    }
    for (long long i = t0; i < 1536LL*1024; i += stride){
        int n = (int)(i >> 10), k2 = (int)(i & 1023);
        float v;
        if (k2 < 512) v = Wx[(long long)(512 + k2)*1536 + n];          // Wx[1][k2][n]
        else { int k = k2 - 512; v = (n < 1024) ? Uh[(long long)(512 + k)*1024 + n] : 0.0f; }
        B3T[i] = f2bf(v);
    }
    for (long long i = t0; i < 512LL*512; i += stride){
        int n = (int)(i >> 9), k = (int)(i & 511);
        UhtT1[i] = f2bf(Uht[(long long)(512 + k)*512 + n]);
    }
    for (long long i = t0; i < 10112LL*512; i += stride){
        int n = (int)(i >> 9), k = (int)(i & 511);
        decpad[i] = (n < 10000) ? f2bf(dec_w[(long long)n*512 + k]) : (unsigned short)0;
    }
    for (long long i = t0; i < 65536; i += stride){
        int b = (int)(i >> 10), c = (int)(i & 1023);
        int l = c >> 9, j = c & 511;
        float v = hidden[((long long)l*64 + b)*512 + j];
        HH[i] = v; HHbf[i] = f2bf(v);                                  // HH[b][l*512+j]
    }
    for (long long i = t0; i < 1024; i += stride) barzone[i] = 0u;
}

// ------------------------------------------------- tiled 128x128 bf16 GEMM --
__global__ __launch_bounds__(256) void gemm128(const unsigned short* __restrict__ A,
    const unsigned short* __restrict__ BT, int M, int N, int K, int mode,
    float* __restrict__ outF, unsigned short* __restrict__ outB,
    const float* __restrict__ bias, int Nreal)
{
    __shared__ unsigned short Ash[128*32];
    __shared__ unsigned short Bsh[128*32];
    const int nT = N >> 7;
    const int mb = blockIdx.x / nT, nb = blockIdx.x % nT;
    const int tid = threadIdx.x;
    const int lane = tid & 63, wId = tid >> 6;
    const int wm = wId >> 1, wn = wId & 1;
    const int ln = lane & 15, kg = lane >> 4;
    f32x4 acc[4][4];
    #pragma unroll
    for (int mt = 0; mt < 4; ++mt)
        #pragma unroll
        for (int nt = 0; nt < 4; ++nt) acc[mt][nt] = f32x4{0.f,0.f,0.f,0.f};

    for (int kc = 0; kc < K; kc += 32){
        #pragma unroll
        for (int it = 0; it < 2; ++it){
            int flat = it*256 + tid;
            int row = flat >> 2, kq = flat & 3;
            *(int4*)(&Ash[flat*8]) = *(const int4*)(A + (long long)(mb*128 + row)*K + kc + kq*8);
            *(int4*)(&Bsh[flat*8]) = *(const int4*)(BT + (long long)(nb*128 + row)*K + kc + kq*8);
        }
        __syncthreads();
        s16x8 af[4], bfv[4];
        #pragma unroll
        for (int mt = 0; mt < 4; ++mt) af[mt]  = *(const s16x8*)(&Ash[(wm*64 + mt*16 + ln)*32 + kg*8]);
        #pragma unroll
        for (int nt = 0; nt < 4; ++nt) bfv[nt] = *(const s16x8*)(&Bsh[(wn*64 + nt*16 + ln)*32 + kg*8]);
        #pragma unroll
        for (int mt = 0; mt < 4; ++mt)
            #pragma unroll
            for (int nt = 0; nt < 4; ++nt)
                acc[mt][nt] = __builtin_amdgcn_mfma_f32_16x16x32_bf16(af[mt], bfv[nt], acc[mt][nt], 0, 0, 0);
        __syncthreads();
    }
    #pragma unroll
    for (int mt = 0; mt < 4; ++mt)
        #pragma unroll
        for (int nt = 0; nt < 4; ++nt)
            #pragma unroll
            for (int r = 0; r < 4; ++r){
                int row = mb*128 + wm*64 + mt*16 + kg*4 + r;   // C/D: col=lane&15, row=(lane>>4)*4+reg
                int col = nb*128 + wn*64 + nt*16 + ln;
                float v = acc[mt][nt][r];
                if (mode == 0){
                    outB[(long long)row*N + col] = f2bf(v);
                } else {
                    if (col < Nreal) outF[(long long)row*Nreal + col] = v + bias[col];
                }
            }
}

// -------------------------------------------------------- persistent GRU ----
// Contention-free barrier: per-block flag lines (128B apart) in MALL.
// Arrival = one sc0sc1 flag store (after vmcnt drain); detection = 16 lanes
// poll 16 DIFFERENT lines in one vector load + ballot. No RMW, no XCD or L1
// assumptions.
static __device__ __forceinline__ void gsync(unsigned int* flags, int blk, unsigned gen){
    SC_WAIT();                       // all this block's sc-stores are MALL-visible
    __syncthreads();
    if (threadIdx.x < 64){
        if (threadIdx.x == 0){
            asm volatile("global_store_dword %0, %1, off sc0 sc1"
                         :: "v"(flags + blk*32), "v"(gen) : "memory");
        }
        const unsigned int* p = flags + (threadIdx.x & (NBG-1))*32;
        unsigned v;
        do {
            asm volatile("global_load_dword %0, %1, off sc0 sc1\n\ts_waitcnt vmcnt(0)"
                         : "=v"(v) : "v"(p) : "memory");
        } while (__ballot(v >= gen) != ~0ull);
    }
    __syncthreads();
}

// Wave-tile GEMM: D[64 n][64 b], A = weights (N,K) from global (cached),
// B = 4 b-fragments from XOR-swizzled LDS. C/D: col(b)=lane&15, row(n)=(lane>>4)*4+reg.
template<int MT, int KIT, int PITCH>
static __device__ __forceinline__ void mmTile(const unsigned short* __restrict__ W,
    const char* __restrict__ lds, int ln, int kg, f32x4 acc[][4])
{
    constexpr int K = KIT * 32;
    #pragma unroll
    for (int mt = 0; mt < MT; ++mt)
        #pragma unroll
        for (int nt = 0; nt < 4; ++nt) acc[mt][nt] = f32x4{0.f,0.f,0.f,0.f};
    #pragma unroll 4
    for (int k = 0; k < KIT; ++k){
        s16x8 bv[4];
        #pragma unroll
        for (int nt = 0; nt < 4; ++nt){
            const int row = nt*16 + ln;
            bv[nt] = *(const s16x8*)(lds + ((row*PITCH + k*64 + kg*16) ^ ((row & 7) << 4)));
        }
        #pragma unroll
        for (int mt = 0; mt < MT; ++mt){
            s16x8 av = *(const s16x8*)(W + (mt*16 + ln)*K + k*32 + kg*8);
            #pragma unroll
            for (int nt = 0; nt < 4; ++nt)
                acc[mt][nt] = __builtin_amdgcn_mfma_f32_16x16x32_bf16(av, bv[nt], acc[mt][nt], 0, 0, 0);
        }
    }
}

__global__ __launch_bounds__(512, 1) void gru_kernel(
    float* __restrict__ HHf, unsigned short* __restrict__ HHbf,
    const unsigned short* __restrict__ UhT0, const unsigned short* __restrict__ UhtT0,
    const unsigned short* __restrict__ B3T,  const unsigned short* __restrict__ UhtT1,
    const unsigned short* __restrict__ WX0,
    unsigned short* __restrict__ rh0, unsigned short* __restrict__ rh1,
    float* __restrict__ z0, float* __restrict__ z1, float* __restrict__ P3,
    unsigned short* __restrict__ H2bf, const float* __restrict__ b_rzh,
    float* __restrict__ outTail, unsigned int* __restrict__ barzone)
{
    __shared__ __align__(16) char smem[131072];   // 128 KB (1 block/CU)
    const int tid = threadIdx.x, lane = tid & 63, wv = tid >> 6, blk = blockIdx.x;
    const int ln = lane & 15, kg = lane >> 4;
    unsigned int* flags = barzone + 256;
    const float* b0 = b_rzh;
    const float* b1 = b_rzh + 1536;
    const bool oddb = (blk & 1) != 0;
    const int ngB = blk >> 1;                     // phase-B tile (S2 even / S4 odd)
    unsigned gen = 0;

    for (int ss = 0; ss <= SEQ; ++ss){
        // ===================== phase A: S1(ss) || S3(ss-1) ==================
        // stage H [64][1024] bf16 -> LDS (pitch 2048, byte ^= (row&7)<<4)
        // 16 loads/thread issued back-to-back, ONE waitcnt (single MALL RT).
        {
            const char* src = (const char*)HHbf;
            i32x4 t[16];
            #pragma unroll
            for (int j = 0; j < 16; ++j)
                SC_LD16_NW(t[j], src + (long long)(tid + j*512)*16);
            SC_WAIT();
            #pragma unroll
            for (int j = 0; j < 16; ++j){
                const int c = tid + j*512;
                *(i32x4*)(smem + ((c*16) ^ (((c >> 7) & 7) << 4))) = t[j];
            }
        }
        __syncthreads();
        if (wv == 0 && ss < SEQ){
            // ---- S1: uh = h0 @ Uh0, tile ng=blk over N=1024
            const int ng = blk;
            f32x4 acc[4][4];
            mmTile<4,16,2048>(UhT0 + ng*64*512, smem, ln, kg, acc);
            const int t = ss;
            #pragma unroll
            for (int mt = 0; mt < 4; ++mt){
                const int nq = ng*64 + mt*16 + kg*4;
                #pragma unroll
                for (int nt = 0; nt < 4; ++nt){
                    const int b = nt*16 + ln;
                    union { ull u; unsigned short s[4]; } wx;
                    wx.u = *(const ull*)(WX0 + (long long)(t*64 + b)*1536 + nq);
                    float sg[4];
                    #pragma unroll
                    for (int r = 0; r < 4; ++r)
                        sg[r] = sigm(acc[mt][nt][r] + bf2f(wx.s[r]) + b0[nq + r]);
                    if (nq < 512){
                        union { ull u; unsigned short s[4]; } h;
                        h.u = *(const ull*)(smem + ((b*2048 + nq*2) ^ ((b & 7) << 4)));
                        float rv[4];
                        #pragma unroll
                        for (int r = 0; r < 4; ++r) rv[r] = sg[r] * bf2f(h.s[r]);
                        sc_st8(rh0 + b*512 + nq, pack4bf(rv));
                    } else {
                        f32x4 zz = {sg[0], sg[1], sg[2], sg[3]};
                        sc_st16(z0 + b*512 + (nq - 512), zz);
                    }
                }
            }
        } else if (ss >= 1 && (wv == 1 || (wv == 2 && !oddb))){
            // ---- S3: [h0|h1] @ B3T, 24 tiles over N=1536
            const int ng = (wv == 1) ? blk : 16 + (blk >> 1);
            f32x4 acc[1][4];
            mmTile<1,32,2048>(B3T + ng*64*1024, smem, ln, kg, acc);
            const int nqb = ng*64;
            #pragma unroll
            for (int mt4 = 0; mt4 < 4; ++mt4){ /* placeholder keeps structure parity */ }
            #pragma unroll
            for (int dummy = 0; dummy < 1; ++dummy){}
            // NOTE: MT=1 covers 16 n; the other 48 n of this 64-tile are done by
            // re-running mmTile with shifted W. Loop 4 sub-tiles of 16 n:
            #pragma unroll
            for (int sub = 0; sub < 4; ++sub){
                f32x4 a1[1][4];
                mmTile<1,32,2048>(B3T + (long long)(nqb + sub*16)*1024, smem, ln, kg, a1);
                const int nq = nqb + sub*16 + kg*4;
                #pragma unroll
                for (int nt = 0; nt < 4; ++nt){
                    const int b = nt*16 + ln;
                    if (nq < 512){
                        union { ull u; unsigned short s[4]; } h;
                        h.u = *(const ull*)(smem + ((b*2048 + (512 + nq)*2) ^ ((b & 7) << 4)));
                        float rv[4];
                        #pragma unroll
                        for (int r = 0; r < 4; ++r)
                            rv[r] = sigm(a1[0][nt][r] + b1[nq + r]) * bf2f(h.s[r]);
                        sc_st8(rh1 + b*512 + nq, pack4bf(rv));
                    } else if (nq < 1024){
                        float sg[4];
                        #pragma unroll
                        for (int r = 0; r < 4; ++r)
                            sg[r] = sigm(a1[0][nt][r] + b1[nq + r]);
                        f32x4 zz = {sg[0], sg[1], sg[2], sg[3]};
                        sc_st16(z1 + b*512 + (nq - 512), zz);
                    } else {
                        sc_st16(P3 + b*512 + (nq - 1024), a1[0][nt]);
                    }
                }
            }
        }
        ++gen; gsync(flags, blk, gen);

        // ===================== phase B: S2(ss) || S4(ss-1) ==================
        // Stage rh + f32 column slices, all issued in one batch:
        //   rh [64][512] bf16 (pitch 1024, swizzled); Zb @65536; Hp @81920;
        //   Pp @98304 (odd blocks only).
        {
            const char* srcR = (const char*)(oddb ? rh1 : rh0);
            const char* srcZ = (const char*)(oddb ? z1 : z0);
            const char* srcH = (const char*)(HHf + (oddb ? 512 : 0));
            const char* srcP = (const char*)P3;
            const int cb0 = ngB*64;
            i32x4 tr[8];
            ull tz[4], th[4], tp[4];
            #pragma unroll
            for (int j = 0; j < 8; ++j)
                SC_LD16_NW(tr[j], srcR + (long long)(tid + j*512)*16);
            #pragma unroll
            for (int j = 0; j < 4; ++j){
                const int c = tid + j*512;
                const int b = c >> 5, ch = c & 31;
                SC_LD8_NW(tz[j], srcZ + (long long)b*2048 + cb0*4 + ch*8);
                SC_LD8_NW(th[j], srcH + (long long)b*4096 + cb0*4 + ch*8);
                if (oddb) SC_LD8_NW(tp[j], srcP + (long long)b*2048 + cb0*4 + ch*8);
            }
            SC_WAIT();
            #pragma unroll
            for (int j = 0; j < 8; ++j){
                const int c = tid + j*512;
                *(i32x4*)(smem + ((c*16) ^ (((c >> 6) & 7) << 4))) = tr[j];
            }
            #pragma unroll
            for (int j = 0; j < 4; ++j){
                const int c = tid + j*512;
                const int b = c >> 5, ch = c & 31;
                const int off = (ch*8) ^ ((b & 15) << 4);
                *(ull*)(smem + 65536 + b*256 + off) = tz[j];
                *(ull*)(smem + 81920 + b*256 + off) = th[j];
                if (oddb) *(ull*)(smem + 98304 + b*256 + off) = tp[j];
            }
        }
        __syncthreads();
        if (wv == 0 && !oddb && ss < SEQ){
            // ---- S2: ht = tanh(wx_h + rh0@Uht0 + b); h0 update. tile ngB.
            f32x4 acc[4][4];
            mmTile<4,16,1024>(UhtT0 + ngB*64*512, smem, ln, kg, acc);
            const int t = ss;
            #pragma unroll
            for (int mt = 0; mt < 4; ++mt){
                const int nq = ngB*64 + mt*16 + kg*4;   // < 512
                const int lc = mt*64 + kg*16;           // local col byte offset
                #pragma unroll
                for (int nt = 0; nt < 4; ++nt){
                    const int b = nt*16 + ln;
                    union { ull u; unsigned short s[4]; } wx;
                    wx.u = *(const ull*)(WX0 + (long long)(t*64 + b)*1536 + 1024 + nq);
                    const int off = lc ^ (ln << 4);
                    const float* zp = (const float*)(smem + 65536 + b*256 + off);
                    const float* hp = (const float*)(smem + 81920 + b*256 + off);
                    float hn[4];
                    #pragma unroll
                    for (int r = 0; r < 4; ++r){
                        float pre = acc[mt][nt][r] + bf2f(wx.s[r]) + b0[1024 + nq + r];
                        float ht = tanh_fast(pre);
                        float z = zp[r];
                        hn[r] = (1.0f - z)*hp[r] + z*ht;
                    }
                    f32x4 hv = {hn[0], hn[1], hn[2], hn[3]};
                    sc_st16(HHf + b*1024 + nq, hv);
                    sc_st8(HHbf + b*1024 + nq, pack4bf(hn));
                }
            }
        } else if (wv == 0 && oddb && ss >= 1){
            // ---- S4: ht = tanh(P3 + rh1@Uht1 + b); h1 update + H2bf. tile ngB.
            f32x4 acc[4][4];
            mmTile<4,16,1024>(UhtT1 + ngB*64*512, smem, ln, kg, acc);
            const int t = ss - 1;
            #pragma unroll
            for (int mt = 0; mt < 4; ++mt){
                const int nq = ngB*64 + mt*16 + kg*4;   // < 512
                const int lc = mt*64 + kg*16;
                #pragma unroll
                for (int nt = 0; nt < 4; ++nt){
                    const int b = nt*16 + ln;
                    const int off = lc ^ (ln << 4);
                    const float* zp = (const float*)(smem + 65536 + b*256 + off);
                    const float* hp = (const float*)(smem + 81920 + b*256 + off);
                    const float* pp = (const float*)(smem + 98304 + b*256 + off);
                    float hn[4];
                    #pragma unroll
                    for (int r = 0; r < 4; ++r){
                        float pre = acc[mt][nt][r] + pp[r] + b1[1024 + nq + r];
                        float ht = tanh_fast(pre);
                        float z = zp[r];
                        hn[r] = (1.0f - z)*hp[r] + z*ht;
                    }
                    f32x4 hv = {hn[0], hn[1], hn[2], hn[3]};
                    sc_st16(HHf + b*1024 + 512 + nq, hv);
                    sc_st8(HHbf + b*1024 + 512 + nq, pack4bf(hn));
                    *(ull*)(H2bf + (long long)(t*64 + b)*512 + nq) = pack4bf(hn);
                }
            }
        }
        ++gen; gsync(flags, blk, gen);
    }

    // h_final tail: out[(l*64+b)*512 + j] = HHf[b*1024 + l*512 + j]
    for (int c = blk*512 + tid; c < 16384; c += NBG*512){
        f32x4 v = sc_ld16(HHf + c*4);
        int b = c >> 8, cc = c & 255, l = cc >> 7, j = (cc & 127) << 2;
        *(f32x4*)(outTail + l*32768 + b*512 + j) = v;
    }
}

// ---------------------------------------------------------------- launch ----
extern "C" void kernel_launch(void* const* d_in, const int* in_sizes, int n_in,
                              void* d_out, int out_size, void* d_ws, size_t ws_size,
                              hipStream_t stream)
{
    const int*   inputs = (const int*)d_in[0];
    const float* hidden = (const float*)d_in[1];
    const float* emb    = (const float*)d_in[2];
    const float* Wx     = (const float*)d_in[3];
    const float* Uh     = (const float*)d_in[4];
    const float* Uht    = (const float*)d_in[5];
    const float* b_rzh  = (const float*)d_in[6];
    const float* dec_w  = (const float*)d_in[7];
    const float* dec_b  = (const float*)d_in[8];
    float* out = (float*)d_out;

    char* w = (char*)d_ws;
    size_t off = 0;
    auto alloc = [&](size_t bytes)->char*{
        char* p = w + off; off = (off + bytes + 255) & ~(size_t)255; return p;
    };
    unsigned short* emb_bf = (unsigned short*)alloc(4096LL*512*2);
    unsigned short* WxT0   = (unsigned short*)alloc(1536LL*512*2);
    unsigned short* WX0    = (unsigned short*)alloc(4096LL*1536*2);
    unsigned short* UhT0   = (unsigned short*)alloc(1024LL*512*2);
    unsigned short* UhtT0  = (unsigned short*)alloc(512LL*512*2);
    unsigned short* B3T    = (unsigned short*)alloc(1536LL*1024*2);
    unsigned short* UhtT1  = (unsigned short*)alloc(512LL*512*2);
    unsigned short* decpad = (unsigned short*)alloc(10112LL*512*2);
    float*          HH     = (float*)alloc(65536*4);
    unsigned short* HHbf   = (unsigned short*)alloc(65536*2);
    unsigned short* rh0    = (unsigned short*)alloc(64*512*2);
    unsigned short* rh1    = (unsigned short*)alloc(64*512*2);
    float*          z0     = (float*)alloc(64*512*4);
    float*          z1     = (float*)alloc(64*512*4);
    float*          P3     = (float*)alloc(64*512*4);
    unsigned short* H2bf   = (unsigned short*)alloc(4096LL*512*2);
    unsigned int*   barzone= (unsigned int*)alloc(4096);
    if (off > ws_size) return;  // workspace too small: fail loudly via absmax

    prep_kernel<<<1024, 256, 0, stream>>>(inputs, hidden, emb, Wx, Uh, Uht, dec_w,
        emb_bf, WxT0, UhT0, UhtT0, B3T, UhtT1, decpad, HH, HHbf, barzone);

    // WX0 = embed @ Wx0  (M=4096, N=1536, K=512), bf16 out
    gemm128<<<dim3(32*12), 256, 0, stream>>>(emb_bf, WxT0, 4096, 1536, 512,
        0, nullptr, WX0, nullptr, 1536);

    // persistent recurrent kernel (16 co-resident blocks, flag-array barrier)
    gru_kernel<<<dim3(NBG), 512, 0, stream>>>(HH, HHbf, UhT0, UhtT0, B3T, UhtT1,
        WX0, rh0, rh1, z0, z1, P3, H2bf, b_rzh, out + 40960000, barzone);

    // decoder: logits = H2 @ dec_w^T + dec_b  (M=4096, N=10112 padded, K=512)
    gemm128<<<dim3(32*79), 256, 0, stream>>>(H2bf, decpad, 4096, 10112, 512,
        1, out, nullptr, dec_b, 10000);
}

// Round 7
// 2069.469 us; speedup vs baseline: 2.3848x; 2.3848x over previous
//
#include <hip/hip_runtime.h>
#include <hip/hip_bf16.h>

// GRU: SEQ=64, BATCH=64, HID=EMB=512, VOCAB=10000, LAYERS=2
// Outputs: logits (64,64,10000) f32 then h_final (2,64,512) f32, concat flat.

#define SEQ 64
#define NPART 16   // worker blocks (elected on ONE XCD; its L2 = coherence point)

typedef short s16x8 __attribute__((ext_vector_type(8)));   // 8 bf16 (4 VGPRs)
typedef float f32x4 __attribute__((ext_vector_type(4)));
typedef unsigned long long ull;

static __device__ __forceinline__ unsigned short f2bf(float f){
    unsigned int u = __float_as_uint(f);
    return (unsigned short)((u + 0x7FFFu + ((u >> 16) & 1u)) >> 16);  // RNE
}
static __device__ __forceinline__ float bf2f(unsigned short s){
    return __uint_as_float(((unsigned int)s) << 16);
}
static __device__ __forceinline__ float sigm(float x){
    return __fdividef(1.0f, 1.0f + __expf(-x));
}
static __device__ __forceinline__ float tanh_fast(float x){
    float ax = fabsf(x);
    float e = __expf(-2.0f * ax);
    float r = __fdividef(1.0f - e, 1.0f + e);
    return copysignf(r, x);
}
static __device__ __forceinline__ ull pack4bf(const float v[4]){
    union { ull u; unsigned short s[4]; } x;
    x.s[0]=f2bf(v[0]); x.s[1]=f2bf(v[1]); x.s[2]=f2bf(v[2]); x.s[3]=f2bf(v[3]);
    return x.u;
}

// ---------------------------------------------------------------- prep ------
__global__ void prep_kernel(const int* __restrict__ inputs, const float* __restrict__ hidden,
    const float* __restrict__ emb, const float* __restrict__ Wx, const float* __restrict__ Uh,
    const float* __restrict__ Uht, const float* __restrict__ dec_w,
    unsigned short* __restrict__ emb_bf, unsigned short* __restrict__ WxT0,
    unsigned short* __restrict__ UhT0, unsigned short* __restrict__ UhtT0,
    unsigned short* __restrict__ B3T, unsigned short* __restrict__ UhtT1,
    unsigned short* __restrict__ decpad,
    float* __restrict__ HH, unsigned short* __restrict__ HHbf, unsigned int* __restrict__ barzone)
{
    const long long stride = (long long)gridDim.x * blockDim.x;
    const long long t0 = (long long)blockIdx.x * blockDim.x + threadIdx.x;
    for (long long i = t0; i < 4096LL*512; i += stride){
        int r = (int)(i >> 9), k = (int)(i & 511);
        emb_bf[i] = f2bf(emb[(long long)inputs[r]*512 + k]);
    }
    for (long long i = t0; i < 1536LL*512; i += stride){
        int n = (int)(i >> 9), k = (int)(i & 511);
        WxT0[i] = f2bf(Wx[(long long)k*1536 + n]);
    }
    for (long long i = t0; i < 1024LL*512; i += stride){
        int n = (int)(i >> 9), k = (int)(i & 511);
        UhT0[i] = f2bf(Uh[(long long)k*1024 + n]);
    }
    for (long long i = t0; i < 512LL*512; i += stride){
        int n = (int)(i >> 9), k = (int)(i & 511);
        UhtT0[i] = f2bf(Uht[(long long)k*512 + n]);
    }
    for (long long i = t0; i < 1536LL*1024; i += stride){
        int n = (int)(i >> 10), k2 = (int)(i & 1023);
        float v;
        if (k2 < 512) v = Wx[(long long)(512 + k2)*1536 + n];          // Wx[1][k2][n]
        else { int k = k2 - 512; v = (n < 1024) ? Uh[(long long)(512 + k)*1024 + n] : 0.0f; }
        B3T[i] = f2bf(v);
    }
    for (long long i = t0; i < 512LL*512; i += stride){
        int n = (int)(i >> 9), k = (int)(i & 511);
        UhtT1[i] = f2bf(Uht[(long long)(512 + k)*512 + n]);
    }
    for (long long i = t0; i < 10112LL*512; i += stride){
        int n = (int)(i >> 9), k = (int)(i & 511);
        decpad[i] = (n < 10000) ? f2bf(dec_w[(long long)n*512 + k]) : (unsigned short)0;
    }
    for (long long i = t0; i < 65536; i += stride){
        int b = (int)(i >> 10), c = (int)(i & 1023);
        int l = c >> 9, j = c & 511;
        float v = hidden[((long long)l*64 + b)*512 + j];
        HH[i] = v; HHbf[i] = f2bf(v);                                  // HH[b][l*512+j]
    }
    for (long long i = t0; i < 1024; i += stride) barzone[i] = 0u;
}

// ------------------------------------------------- tiled 128x128 bf16 GEMM --
__global__ __launch_bounds__(256) void gemm128(const unsigned short* __restrict__ A,
    const unsigned short* __restrict__ BT, int M, int N, int K, int mode,
    float* __restrict__ outF, unsigned short* __restrict__ outB,
    const float* __restrict__ bias, int Nreal)
{
    __shared__ unsigned short Ash[128*32];
    __shared__ unsigned short Bsh[128*32];
    const int nT = N >> 7;
    const int mb = blockIdx.x / nT, nb = blockIdx.x % nT;
    const int tid = threadIdx.x;
    const int lane = tid & 63, wId = tid >> 6;
    const int wm = wId >> 1, wn = wId & 1;
    const int ln = lane & 15, kg = lane >> 4;
    f32x4 acc[4][4];
    #pragma unroll
    for (int mt = 0; mt < 4; ++mt)
        #pragma unroll
        for (int nt = 0; nt < 4; ++nt) acc[mt][nt] = f32x4{0.f,0.f,0.f,0.f};

    for (int kc = 0; kc < K; kc += 32){
        #pragma unroll
        for (int it = 0; it < 2; ++it){
            int flat = it*256 + tid;
            int row = flat >> 2, kq = flat & 3;
            *(int4*)(&Ash[flat*8]) = *(const int4*)(A + (long long)(mb*128 + row)*K + kc + kq*8);
            *(int4*)(&Bsh[flat*8]) = *(const int4*)(BT + (long long)(nb*128 + row)*K + kc + kq*8);
        }
        __syncthreads();
        s16x8 af[4], bfv[4];
        #pragma unroll
        for (int mt = 0; mt < 4; ++mt) af[mt]  = *(const s16x8*)(&Ash[(wm*64 + mt*16 + ln)*32 + kg*8]);
        #pragma unroll
        for (int nt = 0; nt < 4; ++nt) bfv[nt] = *(const s16x8*)(&Bsh[(wn*64 + nt*16 + ln)*32 + kg*8]);
        #pragma unroll
        for (int mt = 0; mt < 4; ++mt)
            #pragma unroll
            for (int nt = 0; nt < 4; ++nt)
                acc[mt][nt] = __builtin_amdgcn_mfma_f32_16x16x32_bf16(af[mt], bfv[nt], acc[mt][nt], 0, 0, 0);
        __syncthreads();
    }
    #pragma unroll
    for (int mt = 0; mt < 4; ++mt)
        #pragma unroll
        for (int nt = 0; nt < 4; ++nt)
            #pragma unroll
            for (int r = 0; r < 4; ++r){
                int row = mb*128 + wm*64 + mt*16 + kg*4 + r;   // C/D: col=lane&15, row=(lane>>4)*4+reg
                int col = nb*128 + wn*64 + nt*16 + ln;
                float v = acc[mt][nt][r];
                if (mode == 0){
                    outB[(long long)row*N + col] = f2bf(v);
                } else {
                    if (col < Nreal) outF[(long long)row*Nreal + col] = v + bias[col];
                }
            }
}

// -------------------------------------------------------- persistent GRU ----
// Workers share one XCD -> plain (cached) loads/stores through the XCD L2.
// Barrier flags live in MALL via sc0sc1 (round-6-proven). buffer_inv (L1-only)
// after each barrier makes plain loads L2-fresh. Poll is bounded (hang-proof).
static __device__ __forceinline__ void gsync(unsigned int* flags, int rank, unsigned gen){
    asm volatile("s_waitcnt vmcnt(0)" ::: "memory");   // plain stores -> L2 visible
    __syncthreads();
    if (threadIdx.x < 64){
        if (threadIdx.x == 0){
            asm volatile("global_store_dword %0, %1, off sc0 sc1"
                         :: "v"(flags + rank*32), "v"(gen) : "memory");
        }
        const unsigned int* p = flags + (threadIdx.x & (NPART-1))*32;
        unsigned v; int it = 0;
        do {
            asm volatile("global_load_dword %0, %1, off sc0 sc1\n\ts_waitcnt vmcnt(0)"
                         : "=v"(v) : "v"(p) : "memory");
        } while (__ballot(v >= gen) != ~0ull && ++it < (1 << 22));
    }
    __syncthreads();
    asm volatile("buffer_inv" ::: "memory");           // L1 invalidate (fresh L2 reads)
}

// Wave-tile GEMM: D[MT*16 n][64 b]. A = weights (N,K) global (L2-cached),
// B = 4 b-fragments from XOR-swizzled LDS. C/D: col(b)=lane&15, row(n)=(lane>>4)*4+reg.
template<int MT, int KIT, int PITCH>
static __device__ __forceinline__ void mmTile(const unsigned short* __restrict__ W,
    const char* __restrict__ lds, int ln, int kg, f32x4 acc[][4])
{
    constexpr int K = KIT * 32;
    #pragma unroll
    for (int mt = 0; mt < MT; ++mt)
        #pragma unroll
        for (int nt = 0; nt < 4; ++nt) acc[mt][nt] = f32x4{0.f,0.f,0.f,0.f};
    #pragma unroll 4
    for (int k = 0; k < KIT; ++k){
        s16x8 bv[4];
        #pragma unroll
        for (int nt = 0; nt < 4; ++nt){
            const int row = nt*16 + ln;
            bv[nt] = *(const s16x8*)(lds + ((row*PITCH + k*64 + kg*16) ^ ((row & 7) << 4)));
        }
        #pragma unroll
        for (int mt = 0; mt < MT; ++mt){
            s16x8 av = *(const s16x8*)(W + (mt*16 + ln)*K + k*32 + kg*8);
            #pragma unroll
            for (int nt = 0; nt < 4; ++nt)
                acc[mt][nt] = __builtin_amdgcn_mfma_f32_16x16x32_bf16(av, bv[nt], acc[mt][nt], 0, 0, 0);
        }
    }
}

__global__ __launch_bounds__(512, 1) void gru_kernel(
    float* __restrict__ HHf, unsigned short* __restrict__ HHbf,
    const unsigned short* __restrict__ UhT0, const unsigned short* __restrict__ UhtT0,
    const unsigned short* __restrict__ B3T,  const unsigned short* __restrict__ UhtT1,
    const unsigned short* __restrict__ WX0,
    unsigned short* __restrict__ rh0, unsigned short* __restrict__ rh1,
    float* __restrict__ z0, float* __restrict__ z1, float* __restrict__ P3,
    unsigned short* __restrict__ H2bf, const float* __restrict__ b_rzh,
    float* __restrict__ outTail, unsigned int* __restrict__ barzone)
{
    __shared__ __align__(16) char smem[131072];   // 128 KB (1 block/CU, all resident)
    __shared__ int s_rank;
    const int tid = threadIdx.x, lane = tid & 63, wv = tid >> 6;
    const int ln = lane & 15, kg = lane >> 4;

    // ---- elect NPART workers sharing one XCC_ID (each ID has 32 resident blocks)
    if (tid == 0){
        unsigned xcc;
        asm volatile("s_getreg_b32 %0, hwreg(HW_REG_XCC_ID)" : "=s"(xcc));
        unsigned my = (xcc & 15u) + 1u;
        unsigned prev = atomicCAS(barzone + 1, 0u, my);
        unsigned tgt = prev ? prev : my;
        int r = -1;
        if (my == tgt) r = (int)atomicAdd(barzone, 1u);
        s_rank = r;
    }
    __syncthreads();
    const int rank = s_rank;
    if (rank < 0 || rank >= NPART) return;       // non-workers exit

    unsigned int* flags = barzone + 256;
    const int gw = rank*8 + wv;                  // 0..127
    const float* b0 = b_rzh;
    const float* b1 = b_rzh + 1536;
    unsigned gen = 0;

    for (int ss = 0; ss <= SEQ; ++ss){
        // ===================== phase A: S1(ss) || S3(ss-1) ==================
        // stage H [64][1024] bf16 -> LDS (pitch 2048, byte ^= (row&7)<<4), plain loads
        {
            const int4* src = (const int4*)HHbf;      // 8192 int4
            int4 t[16];
            #pragma unroll
            for (int j = 0; j < 16; ++j) t[j] = src[tid + j*512];
            #pragma unroll
            for (int j = 0; j < 16; ++j){
                const int c = tid + j*512;
                *(int4*)(smem + ((c*16) ^ (((c >> 7) & 7) << 4))) = t[j];
            }
        }
        __syncthreads();
        if (gw < 32){
            if (ss < SEQ){
                // ---- S1 job gw: n0 = gw*32 of 1024 (uh = h0 @ Uh0)
                const int n0 = gw * 32;
                f32x4 acc[2][4];
                mmTile<2,16,2048>(UhT0 + n0*512, smem, ln, kg, acc);
                const int t = ss;
                #pragma unroll
                for (int mt = 0; mt < 2; ++mt){
                    const int nq = n0 + mt*16 + kg*4;
                    #pragma unroll
                    for (int nt = 0; nt < 4; ++nt){
                        const int b = nt*16 + ln;
                        union { ull u; unsigned short s[4]; } wx;
                        wx.u = *(const ull*)(WX0 + (long long)(t*64 + b)*1536 + nq);
                        float sg[4];
                        #pragma unroll
                        for (int r = 0; r < 4; ++r)
                            sg[r] = sigm(acc[mt][nt][r] + bf2f(wx.s[r]) + b0[nq + r]);
                        if (nq < 512){
                            union { ull u; unsigned short s[4]; } h;
                            h.u = *(const ull*)(smem + ((b*2048 + nq*2) ^ ((b & 7) << 4)));
                            float rv[4];
                            #pragma unroll
                            for (int r = 0; r < 4; ++r) rv[r] = sg[r] * bf2f(h.s[r]);
                            *(ull*)(rh0 + b*512 + nq) = pack4bf(rv);
                        } else {
                            f32x4 zz = {sg[0], sg[1], sg[2], sg[3]};
                            *(f32x4*)(z0 + b*512 + (nq - 512)) = zz;
                        }
                    }
                }
            }
        } else {
            if (ss >= 1){
                // ---- S3 job gw-32: n0 = (gw-32)*16 of 1536 ([h0|h1] @ B3T)
                const int n0 = (gw - 32) * 16;
                f32x4 acc[1][4];
                mmTile<1,32,2048>(B3T + n0*1024, smem, ln, kg, acc);
                const int nq = n0 + kg*4;
                #pragma unroll
                for (int nt = 0; nt < 4; ++nt){
                    const int b = nt*16 + ln;
                    if (nq < 512){
                        union { ull u; unsigned short s[4]; } h;
                        h.u = *(const ull*)(smem + ((b*2048 + (512 + nq)*2) ^ ((b & 7) << 4)));
                        float rv[4];
                        #pragma unroll
                        for (int r = 0; r < 4; ++r)
                            rv[r] = sigm(acc[0][nt][r] + b1[nq + r]) * bf2f(h.s[r]);
                        *(ull*)(rh1 + b*512 + nq) = pack4bf(rv);
                    } else if (nq < 1024){
                        float sg[4];
                        #pragma unroll
                        for (int r = 0; r < 4; ++r)
                            sg[r] = sigm(acc[0][nt][r] + b1[nq + r]);
                        f32x4 zz = {sg[0], sg[1], sg[2], sg[3]};
                        *(f32x4*)(z1 + b*512 + (nq - 512)) = zz;
                    } else {
                        *(f32x4*)(P3 + b*512 + (nq - 1024)) = acc[0][nt];
                    }
                }
            }
        }
        ++gen; gsync(flags, rank, gen);

        // ===================== phase B: S2(ss) || S4(ss-1) ==================
        // ranks 0-3 stage rh0, ranks 4-7 stage rh1 (pitch 1024, swizzled)
        if (rank < 8){
            const int4* src = (const int4*)(rank < 4 ? rh0 : rh1);   // 4096 int4
            int4 t[8];
            #pragma unroll
            for (int j = 0; j < 8; ++j) t[j] = src[tid + j*512];
            #pragma unroll
            for (int j = 0; j < 8; ++j){
                const int c = tid + j*512;
                *(int4*)(smem + ((c*16) ^ (((c >> 6) & 7) << 4))) = t[j];
            }
        }
        __syncthreads();
        if (gw < 32){
            if (ss < SEQ){
                // ---- S2 job gw: n0 = gw*16 of 512 (h0 update)
                const int n0 = gw * 16;
                f32x4 acc[1][4];
                mmTile<1,16,1024>(UhtT0 + n0*512, smem, ln, kg, acc);
                const int t = ss;
                const int nq = n0 + kg*4;
                #pragma unroll
                for (int nt = 0; nt < 4; ++nt){
                    const int b = nt*16 + ln;
                    union { ull u; unsigned short s[4]; } wx;
                    wx.u = *(const ull*)(WX0 + (long long)(t*64 + b)*1536 + 1024 + nq);
                    f32x4 z  = *(const f32x4*)(z0 + b*512 + nq);
                    f32x4 hp = *(const f32x4*)(HHf + b*1024 + nq);
                    float hn[4];
                    #pragma unroll
                    for (int r = 0; r < 4; ++r){
                        float pre = acc[0][nt][r] + bf2f(wx.s[r]) + b0[1024 + nq + r];
                        float ht = tanh_fast(pre);
                        hn[r] = (1.0f - z[r])*hp[r] + z[r]*ht;
                    }
                    f32x4 hv = {hn[0], hn[1], hn[2], hn[3]};
                    *(f32x4*)(HHf + b*1024 + nq) = hv;
                    *(ull*)(HHbf + b*1024 + nq) = pack4bf(hn);
                }
            }
        } else if (gw < 64){
            if (ss >= 1){
                // ---- S4 job gw-32: n0 = (gw-32)*16 of 512 (h1 update + H2bf)
                const int n0 = (gw - 32) * 16;
                f32x4 acc[1][4];
                mmTile<1,16,1024>(UhtT1 + n0*512, smem, ln, kg, acc);
                const int t = ss - 1;
                const int nq = n0 + kg*4;
                #pragma unroll
                for (int nt = 0; nt < 4; ++nt){
                    const int b = nt*16 + ln;
                    f32x4 p3 = *(const f32x4*)(P3 + b*512 + nq);
                    f32x4 z  = *(const f32x4*)(z1 + b*512 + nq);
                    f32x4 hp = *(const f32x4*)(HHf + b*1024 + 512 + nq);
                    float hn[4];
                    #pragma unroll
                    for (int r = 0; r < 4; ++r){
                        float pre = acc[0][nt][r] + p3[r] + b1[1024 + nq + r];
                        float ht = tanh_fast(pre);
                        hn[r] = (1.0f - z[r])*hp[r] + z[r]*ht;
                    }
                    f32x4 hv = {hn[0], hn[1], hn[2], hn[3]};
                    *(f32x4*)(HHf + b*1024 + 512 + nq) = hv;
                    *(ull*)(HHbf + b*1024 + 512 + nq) = pack4bf(hn);
                    *(ull*)(H2bf + (long long)(t*64 + b)*512 + nq) = pack4bf(hn);
                }
            }
        }
        ++gen; gsync(flags, rank, gen);
    }

    // h_final tail: out[(l*64+b)*512 + j] = HHf[b*1024 + l*512 + j]
    for (int c = rank*512 + tid; c < 16384; c += NPART*512){
        f32x4 v = *(const f32x4*)(HHf + c*4);
        int b = c >> 8, cc = c & 255, l = cc >> 7, j = (cc & 127) << 2;
        *(f32x4*)(outTail + l*32768 + b*512 + j) = v;
    }
}

// ---------------------------------------------------------------- launch ----
extern "C" void kernel_launch(void* const* d_in, const int* in_sizes, int n_in,
                              void* d_out, int out_size, void* d_ws, size_t ws_size,
                              hipStream_t stream)
{
    const int*   inputs = (const int*)d_in[0];
    const float* hidden = (const float*)d_in[1];
    const float* emb    = (const float*)d_in[2];
    const float* Wx     = (const float*)d_in[3];
    const float* Uh     = (const float*)d_in[4];
    const float* Uht    = (const float*)d_in[5];
    const float* b_rzh  = (const float*)d_in[6];
    const float* dec_w  = (const float*)d_in[7];
    const float* dec_b  = (const float*)d_in[8];
    float* out = (float*)d_out;

    char* w = (char*)d_ws;
    size_t off = 0;
    auto alloc = [&](size_t bytes)->char*{
        char* p = w + off; off = (off + bytes + 255) & ~(size_t)255; return p;
    };
    unsigned short* emb_bf = (unsigned short*)alloc(4096LL*512*2);
    unsigned short* WxT0   = (unsigned short*)alloc(1536LL*512*2);
    unsigned short* WX0    = (unsigned short*)alloc(4096LL*1536*2);
    unsigned short* UhT0   = (unsigned short*)alloc(1024LL*512*2);
    unsigned short* UhtT0  = (unsigned short*)alloc(512LL*512*2);
    unsigned short* B3T    = (unsigned short*)alloc(1536LL*1024*2);
    unsigned short* UhtT1  = (unsigned short*)alloc(512LL*512*2);
    unsigned short* decpad = (unsigned short*)alloc(10112LL*512*2);
    float*          HH     = (float*)alloc(65536*4);
    unsigned short* HHbf   = (unsigned short*)alloc(65536*2);
    unsigned short* rh0    = (unsigned short*)alloc(64*512*2);
    unsigned short* rh1    = (unsigned short*)alloc(64*512*2);
    float*          z0     = (float*)alloc(64*512*4);
    float*          z1     = (float*)alloc(64*512*4);
    float*          P3     = (float*)alloc(64*512*4);
    unsigned short* H2bf   = (unsigned short*)alloc(4096LL*512*2);
    unsigned int*   barzone= (unsigned int*)alloc(4096);
    if (off > ws_size) return;  // workspace too small: fail loudly via absmax

    prep_kernel<<<1024, 256, 0, stream>>>(inputs, hidden, emb, Wx, Uh, Uht, dec_w,
        emb_bf, WxT0, UhT0, UhtT0, B3T, UhtT1, decpad, HH, HHbf, barzone);

    // WX0 = embed @ Wx0  (M=4096, N=1536, K=512), bf16 out
    gemm128<<<dim3(32*12), 256, 0, stream>>>(emb_bf, WxT0, 4096, 1536, 512,
        0, nullptr, WX0, nullptr, 1536);

    // persistent recurrent kernel: 256 blocks, 16 workers on one XCD
    gru_kernel<<<dim3(256), 512, 0, stream>>>(HH, HHbf, UhT0, UhtT0, B3T, UhtT1,
        WX0, rh0, rh1, z0, z1, P3, H2bf, b_rzh, out + 40960000, barzone);

    // decoder: logits = H2 @ dec_w^T + dec_b  (M=4096, N=10112 padded, K=512)
    gemm128<<<dim3(32*79), 256, 0, stream>>>(H2bf, decpad, 4096, 10112, 512,
        1, out, nullptr, dec_b, 10000);
}